// Round 7
// baseline (421.297 us; speedup 1.0000x reference)
//
#include <hip/hip_runtime.h>

#define B_ 64
#define T_ 243
#define J_ 17
#define C_ 128
#define JC (J_*C_)            // 2176
#define NTOT (B_*T_*J_*C_)    // 33841152

// LDS layout (bytes):
//   [0,      65536)  ylds  : bf16 [256][128], swizzled: byte = r*256 + (col_byte ^ ((r&7)<<4))
//   [65536,  67584)  nbr   : u64 [256]  (4 x u16 idx)
//   [67584,  68608)  bnw_s : f32 [256] (pre-scaled)
//   [68608,  69632)  bnb_s : f32 [256]
//   [69632,  70144)  bias_s: f32 [128] (Ub+Vb)
//   [70144,  70656)  ls_s  : f32 [128]
#define YOFF    0
#define NBROFF  65536
#define BNWOFF  67584
#define BNBOFF  68608
#define BIASOFF 69632
#define LSOFF   70144
#define SMEM_BYTES 70656

typedef short bf16x8 __attribute__((ext_vector_type(8)));
typedef float f32x4 __attribute__((ext_vector_type(4)));

__device__ __forceinline__ unsigned short f2bf(float f){
  unsigned u = __float_as_uint(f);
  u += 0x7fffu + ((u >> 16) & 1u);   // RNE
  return (unsigned short)(u >> 16);
}
__device__ __forceinline__ unsigned pk2(float a, float b){
  return (unsigned)f2bf(a) | ((unsigned)f2bf(b) << 16);
}
__device__ __forceinline__ bf16x8 pack8(float4 a, float4 b){
  union { bf16x8 v; unsigned u[4]; } r;
  r.u[0]=pk2(a.x,a.y); r.u[1]=pk2(a.z,a.w); r.u[2]=pk2(b.x,b.y); r.u[3]=pk2(b.z,b.w);
  return r.v;
}

#define LOF(u) __uint_as_float(((unsigned)(u))<<16)
#define HRF(u) __uint_as_float((unsigned)(u))        // hi bf16 with dirty low mantissa (ok, trunc later)
// truncating pack of two f32 into bf16 pair: {lo=a[31:16], hi=b[31:16]}
#define PKT(a,b) __builtin_amdgcn_perm(__float_as_uint(b), __float_as_uint(a), 0x07060302u)

#define UNPK(q,f0,f1,f2,f3) do{ unsigned lo_=(unsigned)(q), hi_=(unsigned)((q)>>32); \
  f0=__uint_as_float(lo_<<16); f1=__uint_as_float(lo_&0xffff0000u); \
  f2=__uint_as_float(hi_<<16); f3=__uint_as_float(hi_&0xffff0000u);}while(0)

// 7-op insert of x into descending (a0>=a1>=a2>=a3)
#define PINS(x, a0,a1,a2,a3) do { \
  float t_ = fmaxf(a0,(x)), m_ = fminf(a0,(x)); a0 = t_; \
  float t2_ = fmaxf(a1,m_); m_ = fminf(a1,m_); a1 = t2_; \
  float t3_ = fmaxf(a2,m_); m_ = fminf(a2,m_); a2 = t3_; \
  a3 = fmaxf(a3,m_); \
} while(0)
#define MM(p,q) do { float h_=fmaxf(p,q); q=fminf(p,q); p=h_; } while(0)

extern "C" __global__ void __launch_bounds__(1024, 8)
graphblock_kernel(const float* __restrict__ x, const float* __restrict__ att,
                  const float* __restrict__ lnw, const float* __restrict__ lnb,
                  const float* __restrict__ Uw, const float* __restrict__ Ubv,
                  const float* __restrict__ Vw, const float* __restrict__ Vbv,
                  const float* __restrict__ bnw, const float* __restrict__ bnb,
                  const float* __restrict__ ls1, float* __restrict__ out)
{
  extern __shared__ char smem[];
  const int tid = threadIdx.x;
  const int w = tid >> 6, l = tid & 63;
  const int lr = l & 15, lg = l >> 4;
  const int n = blockIdx.x, b = n / J_, j = n % J_;
  const long nbase = (long)b*T_*JC + (long)j*C_;
  const int cs = w & 7, rh = w >> 3;
  const int ch0 = cs*16 + lg*4;

  // ---- table staging ----
  if (tid < 256) {
    bool v = tid < T_;
    ((float*)(smem+BNWOFF))[tid] = v ? bnw[tid]*rsqrtf(1.0f+1e-5f) : 0.f;
    ((float*)(smem+BNBOFF))[tid] = v ? bnb[tid] : 0.f;
  } else if (tid < 384) {
    int c = tid - 256;
    ((float*)(smem+BIASOFF))[c] = Ubv[c] + Vbv[c];
    ((float*)(smem+LSOFF))[c]   = ls1[c];
  }

  // ---- Phase A: LayerNorm (float4 loads, 2 rows per wave-iter) ----
  {
    const int lh = l >> 5, lc = l & 31;
    const float4 lw4 = *(const float4*)(lnw + lc*4);
    const float4 lb4 = *(const float4*)(lnb + lc*4);
    #pragma unroll
    for (int i=0;i<8;i++){
      int r = i*32 + w*2 + lh;
      unsigned p0=0u, p1=0u;
      if (r < T_) {
        float4 p = *(const float4*)(x + nbase + (long)r*JC + lc*4);
        float s = (p.x+p.y)+(p.z+p.w);
        float q = (p.x*p.x+p.y*p.y)+(p.z*p.z+p.w*p.w);
        #pragma unroll
        for (int m=1;m<32;m<<=1){ s += __shfl_xor(s,m,64); q += __shfl_xor(q,m,64); }
        float mu = s*(1.f/128.f);
        float rs = rsqrtf(q*(1.f/128.f)-mu*mu+1e-5f);
        p0 = pk2((p.x-mu)*rs*lw4.x+lb4.x, (p.y-mu)*rs*lw4.y+lb4.y);
        p1 = pk2((p.z-mu)*rs*lw4.z+lb4.z, (p.w-mu)*rs*lw4.w+lb4.w);
      }
      char* dst = smem + YOFF + r*256 + ((8*lc) ^ ((r&7)<<4));
      ((unsigned*)dst)[0]=p0; ((unsigned*)dst)[1]=p1;
    }
  }
  __syncthreads();   // barrier 1: ylds + tables ready

  // ---- Phase C: sim (MFMA) + in-register top-4 ----
  {
    const int ar = w*16 + lr;
    bf16x8 afr[4];
    #pragma unroll
    for (int kk=0;kk<4;kk++)
      afr[kk] = *(const bf16x8*)(smem + YOFF + ar*256 + ((kk*64+lg*16) ^ ((ar&7)<<4)));
    float v0[4],v1[4],v2[4],v3[4];
    #pragma unroll
    for (int r=0;r<4;r++){ v0[r]=-3e38f; v1[r]=-3e38f; v2[r]=-3e38f; v3[r]=-3e38f; }
    #pragma unroll 4
    for (int st=0; st<16; st++){
      const int br = st*16 + lr;
      f32x4 acc = {0.f,0.f,0.f,0.f};
      #pragma unroll
      for (int kk=0;kk<4;kk++){
        bf16x8 bfr = *(const bf16x8*)(smem + YOFF + br*256 + ((kk*64+lg*16) ^ ((br&7)<<4)));
        acc = __builtin_amdgcn_mfma_f32_16x16x32_bf16(afr[kk], bfr, acc, 0,0,0);
      }
      const int sidx = st*16 + lr;
      const bool okc = sidx < T_;
      #pragma unroll
      for (int reg=0;reg<4;reg++){
        unsigned u = (__float_as_uint(acc[reg]) & 0xffffff00u) | (unsigned)sidx;
        float pv = okc ? __uint_as_float(u) : -3e38f;
        PINS(pv, v0[reg],v1[reg],v2[reg],v3[reg]);
      }
    }
    #pragma unroll
    for (int m=1;m<16;m<<=1){
      #pragma unroll
      for (int reg=0;reg<4;reg++){
        float c0=__shfl_xor(v0[reg],m,64), c1=__shfl_xor(v1[reg],m,64),
              c2=__shfl_xor(v2[reg],m,64), c3=__shfl_xor(v3[reg],m,64);
        float d0=fmaxf(v0[reg],c3), d1=fmaxf(v1[reg],c2),
              d2=fmaxf(v2[reg],c1), d3=fmaxf(v3[reg],c0);
        MM(d0,d1); MM(d2,d3); MM(d0,d2); MM(d1,d3); MM(d1,d2);
        v0[reg]=d0; v1[reg]=d1; v2[reg]=d2; v3[reg]=d3;
      }
    }
    if (lr==0){
      #pragma unroll
      for (int reg=0;reg<4;reg++){
        int row = w*16 + lg*4 + reg;
        unsigned long long pk =
            (unsigned long long)(__float_as_uint(v0[reg]) & 0xffu)
          | ((unsigned long long)(__float_as_uint(v1[reg]) & 0xffu) << 16)
          | ((unsigned long long)(__float_as_uint(v2[reg]) & 0xffu) << 32)
          | ((unsigned long long)(__float_as_uint(v3[reg]) & 0xffu) << 48);
        *(unsigned long long*)(smem + NBROFF + row*8) = pk;
      }
    }
  }

  // ---- load + pack weights (latency hidden by other waves finishing sim) ----
  bf16x8 ufr[4], vfr[4];
  {
    const int crw = cs*16 + lr;
    #pragma unroll
    for (int kk=0;kk<4;kk++){
      const float4* pu = (const float4*)(Uw + crw*C_ + kk*32 + lg*8);
      ufr[kk] = pack8(pu[0], pu[1]);
      const float4* pv = (const float4*)(Vw + crw*C_ + kk*32 + lg*8);
      float4 a = pv[0], c = pv[1];
      a.x*=0.25f; a.y*=0.25f; a.z*=0.25f; a.w*=0.25f;
      c.x*=0.25f; c.y*=0.25f; c.z*=0.25f; c.w*=0.25f;
      vfr[kk] = pack8(a, c);
    }
  }
  __syncthreads();   // barrier 2: nbr ready (y unchanged)

  // ---- UV pass: accU = y@Uw^T, accV = (0.25*sum_nbr y)@Vw^T, fused epilogue ----
  #pragma unroll 2
  for (int tt=0; tt<8; tt++){
    const int tile = rh*8 + tt;
    const int t = tile*16 + lr;
    unsigned long long nb = *(const unsigned long long*)(smem + NBROFF + t*8);
    const int s0 = (int)(nb & 0xffu), s1 = (int)((nb>>16)&0xffu),
              s2 = (int)((nb>>32)&0xffu), s3 = (int)((nb>>48)&0xffu);
    const int sw0=(s0&7)<<4, sw1=(s1&7)<<4, sw2=(s2&7)<<4, sw3=(s3&7)<<4;
    const char* r0 = smem + YOFF + s0*256;
    const char* r1 = smem + YOFF + s1*256;
    const char* r2 = smem + YOFF + s2*256;
    const char* r3 = smem + YOFF + s3*256;
    f32x4 accU = {0.f,0.f,0.f,0.f}, accV = {0.f,0.f,0.f,0.f};
    #pragma unroll
    for (int kk=0;kk<4;kk++){
      const int co = kk*64 + lg*16;
      bf16x8 yf = *(const bf16x8*)(smem + YOFF + t*256 + (co ^ ((t&7)<<4)));
      accU = __builtin_amdgcn_mfma_f32_16x16x32_bf16(ufr[kk], yf, accU, 0,0,0);
      uint4 q;
      float zl0,zh0,zl1,zh1,zl2,zh2,zl3,zh3;
      q = *(const uint4*)(r0 + (co ^ sw0));
      zl0 =LOF(q.x); zh0 =HRF(q.x); zl1 =LOF(q.y); zh1 =HRF(q.y);
      zl2 =LOF(q.z); zh2 =HRF(q.z); zl3 =LOF(q.w); zh3 =HRF(q.w);
      q = *(const uint4*)(r1 + (co ^ sw1));
      zl0+=LOF(q.x); zh0+=HRF(q.x); zl1+=LOF(q.y); zh1+=HRF(q.y);
      zl2+=LOF(q.z); zh2+=HRF(q.z); zl3+=LOF(q.w); zh3+=HRF(q.w);
      q = *(const uint4*)(r2 + (co ^ sw2));
      zl0+=LOF(q.x); zh0+=HRF(q.x); zl1+=LOF(q.y); zh1+=HRF(q.y);
      zl2+=LOF(q.z); zh2+=HRF(q.z); zl3+=LOF(q.w); zh3+=HRF(q.w);
      q = *(const uint4*)(r3 + (co ^ sw3));
      zl0+=LOF(q.x); zh0+=HRF(q.x); zl1+=LOF(q.y); zh1+=HRF(q.y);
      zl2+=LOF(q.z); zh2+=HRF(q.z); zl3+=LOF(q.w); zh3+=HRF(q.w);
      union { bf16x8 v; unsigned u[4]; } zz;
      zz.u[0]=PKT(zl0,zh0); zz.u[1]=PKT(zl1,zh1);
      zz.u[2]=PKT(zl2,zh2); zz.u[3]=PKT(zl3,zh3);
      accV = __builtin_amdgcn_mfma_f32_16x16x32_bf16(vfr[kk], zz.v, accV, 0,0,0);
    }
    // epilogue for this tile
    const bool ok = t < T_;
    const float bw = ((const float*)(smem+BNWOFF))[t];
    const float bb = ((const float*)(smem+BNBOFF))[t];
    const float4 ubvb = *(const float4*)(smem + BIASOFF + ch0*4);
    const float4 ls4  = *(const float4*)(smem + LSOFF   + ch0*4);
    unsigned long long yq = *(const unsigned long long*)(smem + YOFF + t*256 + ((2*ch0) ^ ((t&7)<<4)));
    float yo0,yo1,yo2,yo3; UNPK(yq,yo0,yo1,yo2,yo3);
    const long g = nbase + (long)t*JC + ch0;
    float4 x4 = {0,0,0,0}, a4 = {0,0,0,0};
    if (ok){ x4 = *(const float4*)(x+g); a4 = *(const float4*)(att+g); }
    f32x4 o, gf;
    {
      float h = (accU[0] + accV[0] + ubvb.x)*bw + bb;
      float gx = ls4.x * fmaxf(0.f, yo0 + h);
      o[0] = gx + a4.x + x4.x; gf[0] = gx*0.5f;
    }{
      float h = (accU[1] + accV[1] + ubvb.y)*bw + bb;
      float gx = ls4.y * fmaxf(0.f, yo1 + h);
      o[1] = gx + a4.y + x4.y; gf[1] = gx*0.5f;
    }{
      float h = (accU[2] + accV[2] + ubvb.z)*bw + bb;
      float gx = ls4.z * fmaxf(0.f, yo2 + h);
      o[2] = gx + a4.z + x4.z; gf[2] = gx*0.5f;
    }{
      float h = (accU[3] + accV[3] + ubvb.w)*bw + bb;
      float gx = ls4.w * fmaxf(0.f, yo3 + h);
      o[3] = gx + a4.w + x4.w; gf[3] = gx*0.5f;
    }
    if (ok){
      *(f32x4*)(out+g)      = o;
      *(f32x4*)(out+NTOT+g) = gf;
    }
  }
}

extern "C" void kernel_launch(void* const* d_in, const int* in_sizes, int n_in,
                              void* d_out, int out_size, void* d_ws, size_t ws_size,
                              hipStream_t stream) {
  hipFuncSetAttribute(reinterpret_cast<const void*>(graphblock_kernel),
                      hipFuncAttributeMaxDynamicSharedMemorySize, SMEM_BYTES);
  dim3 grid(B_ * J_);
  dim3 block(1024);
  graphblock_kernel<<<grid, block, SMEM_BYTES, stream>>>(
      (const float*)d_in[0],  // x
      (const float*)d_in[1],  // attention_feat
      (const float*)d_in[2],  // ln_w
      (const float*)d_in[3],  // ln_b
      (const float*)d_in[4],  // Uw
      (const float*)d_in[5],  // Ub
      (const float*)d_in[6],  // Vw
      (const float*)d_in[7],  // Vb
      (const float*)d_in[8],  // bn_w
      (const float*)d_in[9],  // bn_b
      (const float*)d_in[10], // ls1
      (float*)d_out);
}

// Round 8
// 216.676 us; speedup vs baseline: 1.9444x; 1.9444x over previous
//
#include <hip/hip_runtime.h>

#define B_ 64
#define T_ 243
#define J_ 17
#define C_ 128
#define JC (J_*C_)            // 2176
#define NTOT (B_*T_*J_*C_)    // 33841152

// LDS layout (bytes). fp8 rows padded to 136 B (bank de-alias).
//   [0,     34816)  ylds : fp8 [256][136]
//   [34816, 69632)  yv   : fp8 [256][136]  (0.25*(y@Vw^T+Vb))
//   [69632, 71680)  nbr  : u64 [256]
//   [71680, 72704)  bnw_s: f32 [256] (pre-scaled)
//   [72704, 73728)  bnb_s: f32 [256]
//   [73728, 74240)  ub_s : f32 [128]
//   [74240, 74752)  ls_s : f32 [128]
#define YOFF    0
#define YVOFF   34816
#define NBROFF  69632
#define BNWOFF  71680
#define BNBOFF  72704
#define UBOFF   73728
#define LSOFF   74240
#define SMEM_BYTES 74752
#define YSTR 136

typedef float f32x4 __attribute__((ext_vector_type(4)));
typedef float f32x2 __attribute__((ext_vector_type(2)));

// pack 4 f32 -> 4 fp8(e4m3) in one dword
__device__ __forceinline__ unsigned pkf8(float a, float b, float c, float d){
  int p = __builtin_amdgcn_cvt_pk_fp8_f32(a, b, 0, false);
  p = __builtin_amdgcn_cvt_pk_fp8_f32(c, d, p, true);
  return (unsigned)p;
}

// 7-op insert of x into descending (a0>=a1>=a2>=a3)
#define PINS(x, a0,a1,a2,a3) do { \
  float t_ = fmaxf(a0,(x)), m_ = fminf(a0,(x)); a0 = t_; \
  float t2_ = fmaxf(a1,m_); m_ = fminf(a1,m_); a1 = t2_; \
  float t3_ = fmaxf(a2,m_); m_ = fminf(a2,m_); a2 = t3_; \
  a3 = fmaxf(a3,m_); \
} while(0)
#define MM(p,q) do { float h_=fmaxf(p,q); q=fminf(p,q); p=h_; } while(0)

extern "C" __global__ void __launch_bounds__(1024, 8)
graphblock_kernel(const float* __restrict__ x, const float* __restrict__ att,
                  const float* __restrict__ lnw, const float* __restrict__ lnb,
                  const float* __restrict__ Uw, const float* __restrict__ Ubv,
                  const float* __restrict__ Vw, const float* __restrict__ Vbv,
                  const float* __restrict__ bnw, const float* __restrict__ bnb,
                  const float* __restrict__ ls1, float* __restrict__ out)
{
  extern __shared__ char smem[];
  const int tid = threadIdx.x;
  const int w = tid >> 6, l = tid & 63;
  const int lr = l & 15, lg = l >> 4;
  const int n = blockIdx.x, b = n / J_, j = n % J_;
  const long nbase = (long)b*T_*JC + (long)j*C_;
  const int cs = w & 7, rh = w >> 3;
  const int ch0 = cs*16 + lg*4;        // lane's 4-channel base in UV passes

  // ---- table staging ----
  if (tid < 256) {
    bool v = tid < T_;
    ((float*)(smem+BNWOFF))[tid] = v ? bnw[tid]*rsqrtf(1.0f+1e-5f) : 0.f;
    ((float*)(smem+BNBOFF))[tid] = v ? bnb[tid] : 0.f;
  } else if (tid < 384) {
    int c = tid - 256;
    ((float*)(smem+UBOFF))[c] = Ubv[c];
    ((float*)(smem+LSOFF))[c] = ls1[c];
  }

  // ---- Phase A: LayerNorm -> ylds fp8 (2 rows per wave-iter) ----
  {
    const int lh = l >> 5, lc = l & 31;
    const float4 lw4 = *(const float4*)(lnw + lc*4);
    const float4 lb4 = *(const float4*)(lnb + lc*4);
    #pragma unroll
    for (int i=0;i<8;i++){
      int r = i*32 + w*2 + lh;
      unsigned pk = 0u;
      if (r < T_) {
        float4 p = *(const float4*)(x + nbase + (long)r*JC + lc*4);
        float s = (p.x+p.y)+(p.z+p.w);
        float q = (p.x*p.x+p.y*p.y)+(p.z*p.z+p.w*p.w);
        #pragma unroll
        for (int m=1;m<32;m<<=1){ s += __shfl_xor(s,m,64); q += __shfl_xor(q,m,64); }
        float mu = s*(1.f/128.f);
        float rs = rsqrtf(q*(1.f/128.f)-mu*mu+1e-5f);
        pk = pkf8((p.x-mu)*rs*lw4.x+lb4.x, (p.y-mu)*rs*lw4.y+lb4.y,
                  (p.z-mu)*rs*lw4.z+lb4.z, (p.w-mu)*rs*lw4.w+lb4.w);
      }
      *(unsigned*)(smem + YOFF + r*YSTR + lc*4) = pk;
    }
  }
  __syncthreads();   // barrier 1: ylds + tables ready

  // ---- Phase C: sim (fp8 MFMA) + in-register top-4 ----
  {
    const int ar = w*16 + lr;           // wave owns 16 t-rows
    long afr[4];
    #pragma unroll
    for (int kk=0;kk<4;kk++)
      afr[kk] = *(const long*)(smem + YOFF + ar*YSTR + kk*32 + lg*8);
    float v0[4],v1[4],v2[4],v3[4];
    #pragma unroll
    for (int r=0;r<4;r++){ v0[r]=-3e38f; v1[r]=-3e38f; v2[r]=-3e38f; v3[r]=-3e38f; }
    #pragma unroll 4
    for (int st=0; st<16; st++){
      f32x4 acc = {0.f,0.f,0.f,0.f};
      #pragma unroll
      for (int kk=0;kk<4;kk++){
        long bfr = *(const long*)(smem + YOFF + (st*16+lr)*YSTR + kk*32 + lg*8);
        acc = __builtin_amdgcn_mfma_f32_16x16x32_fp8_fp8(afr[kk], bfr, acc, 0,0,0);
      }
      const int sidx = st*16 + lr;
      const bool okc = sidx < T_;
      #pragma unroll
      for (int reg=0;reg<4;reg++){
        unsigned u = (__float_as_uint(acc[reg]) & 0xffffff00u) | (unsigned)sidx;
        float pv = okc ? __uint_as_float(u) : -3e38f;
        PINS(pv, v0[reg],v1[reg],v2[reg],v3[reg]);
      }
    }
    #pragma unroll
    for (int m=1;m<16;m<<=1){
      #pragma unroll
      for (int reg=0;reg<4;reg++){
        float c0=__shfl_xor(v0[reg],m,64), c1=__shfl_xor(v1[reg],m,64),
              c2=__shfl_xor(v2[reg],m,64), c3=__shfl_xor(v3[reg],m,64);
        float d0=fmaxf(v0[reg],c3), d1=fmaxf(v1[reg],c2),
              d2=fmaxf(v2[reg],c1), d3=fmaxf(v3[reg],c0);
        MM(d0,d1); MM(d2,d3); MM(d0,d2); MM(d1,d3); MM(d1,d2);
        v0[reg]=d0; v1[reg]=d1; v2[reg]=d2; v3[reg]=d3;
      }
    }
    if (lr==0){
      #pragma unroll
      for (int reg=0;reg<4;reg++){
        int row = w*16 + lg*4 + reg;
        unsigned long long pk =
            (unsigned long long)(__float_as_uint(v0[reg]) & 0xffu)
          | ((unsigned long long)(__float_as_uint(v1[reg]) & 0xffu) << 16)
          | ((unsigned long long)(__float_as_uint(v2[reg]) & 0xffu) << 32)
          | ((unsigned long long)(__float_as_uint(v3[reg]) & 0xffu) << 48);
        *(unsigned long long*)(smem + NBROFF + row*8) = pk;
      }
    }
  }

  // ---- load + quantize weights to fp8 frags (A-operand: row=out-channel) ----
  long ufr[4], vfr[4];
  {
    const int crw = cs*16 + lr;
    #pragma unroll
    for (int kk=0;kk<4;kk++){
      const float4* pu = (const float4*)(Uw + crw*C_ + kk*32 + lg*8);
      float4 a = pu[0], c = pu[1];
      union { long v; unsigned u[2]; } r;
      r.u[0] = pkf8(a.x,a.y,a.z,a.w); r.u[1] = pkf8(c.x,c.y,c.z,c.w);
      ufr[kk] = r.v;
      const float4* pv = (const float4*)(Vw + crw*C_ + kk*32 + lg*8);
      a = pv[0]; c = pv[1];
      r.u[0] = pkf8(a.x,a.y,a.z,a.w); r.u[1] = pkf8(c.x,c.y,c.z,c.w);
      vfr[kk] = r.v;
    }
  }
  const float4 vb4 = *(const float4*)(Vbv + ch0);

  // ---- Pass 1: yv = 0.25*(y@Vw^T + Vb) -> fp8 LDS (wave: 8 tiles x its slice) ----
  #pragma unroll 2
  for (int tt=0; tt<8; tt++){
    const int t = (rh*8+tt)*16 + lr;
    f32x4 accV = {0.f,0.f,0.f,0.f};
    #pragma unroll
    for (int kk=0;kk<4;kk++){
      long yf = *(const long*)(smem + YOFF + t*YSTR + kk*32 + lg*8);
      accV = __builtin_amdgcn_mfma_f32_16x16x32_fp8_fp8(vfr[kk], yf, accV, 0,0,0);
    }
    *(unsigned*)(smem + YVOFF + t*YSTR + ch0) =
        pkf8(0.25f*(accV[0]+vb4.x), 0.25f*(accV[1]+vb4.y),
             0.25f*(accV[2]+vb4.z), 0.25f*(accV[3]+vb4.w));
  }
  __syncthreads();   // barrier 2: nbr + yv ready

  // ---- Pass 2: yU MFMA + gather + BN + ReLU + epilogue ----
  const float4 ub4 = *(const float4*)((const float*)(smem+UBOFF) + ch0);
  const float4 ls4 = *(const float4*)((const float*)(smem+LSOFF) + ch0);
  #pragma unroll 2
  for (int tt=0; tt<8; tt++){
    const int t = (rh*8+tt)*16 + lr;
    f32x4 accU = {0.f,0.f,0.f,0.f};
    #pragma unroll
    for (int kk=0;kk<4;kk++){
      long yf = *(const long*)(smem + YOFF + t*YSTR + kk*32 + lg*8);
      accU = __builtin_amdgcn_mfma_f32_16x16x32_fp8_fp8(ufr[kk], yf, accU, 0,0,0);
    }
    const bool ok = t < T_;
    const long g = nbase + (long)t*JC + ch0;
    float4 x4 = {0,0,0,0}, a4 = {0,0,0,0};
    if (ok){ x4 = *(const float4*)(x+g); a4 = *(const float4*)(att+g); }
    unsigned long long nb = *(const unsigned long long*)(smem + NBROFF + t*8);
    const int s0 = (int)(nb & 0xffu), s1 = (int)((nb>>16)&0xffu),
              s2 = (int)((nb>>32)&0xffu), s3 = (int)((nb>>48)&0xffu);
    float ag0=0,ag1=0,ag2=0,ag3=0;
    {
      unsigned q; f32x2 e, o2;
      q = *(const unsigned*)(smem+YVOFF + s0*YSTR + ch0);
      e = __builtin_amdgcn_cvt_pk_f32_fp8(q,false); o2 = __builtin_amdgcn_cvt_pk_f32_fp8(q,true);
      ag0+=e[0]; ag1+=e[1]; ag2+=o2[0]; ag3+=o2[1];
      q = *(const unsigned*)(smem+YVOFF + s1*YSTR + ch0);
      e = __builtin_amdgcn_cvt_pk_f32_fp8(q,false); o2 = __builtin_amdgcn_cvt_pk_f32_fp8(q,true);
      ag0+=e[0]; ag1+=e[1]; ag2+=o2[0]; ag3+=o2[1];
      q = *(const unsigned*)(smem+YVOFF + s2*YSTR + ch0);
      e = __builtin_amdgcn_cvt_pk_f32_fp8(q,false); o2 = __builtin_amdgcn_cvt_pk_f32_fp8(q,true);
      ag0+=e[0]; ag1+=e[1]; ag2+=o2[0]; ag3+=o2[1];
      q = *(const unsigned*)(smem+YVOFF + s3*YSTR + ch0);
      e = __builtin_amdgcn_cvt_pk_f32_fp8(q,false); o2 = __builtin_amdgcn_cvt_pk_f32_fp8(q,true);
      ag0+=e[0]; ag1+=e[1]; ag2+=o2[0]; ag3+=o2[1];
    }
    float yo0,yo1,yo2,yo3;
    {
      unsigned q = *(const unsigned*)(smem + YOFF + t*YSTR + ch0);
      f32x2 e = __builtin_amdgcn_cvt_pk_f32_fp8(q,false);
      f32x2 o2 = __builtin_amdgcn_cvt_pk_f32_fp8(q,true);
      yo0=e[0]; yo1=e[1]; yo2=o2[0]; yo3=o2[1];
    }
    const float bw = ((const float*)(smem+BNWOFF))[t];
    const float bb = ((const float*)(smem+BNBOFF))[t];
    f32x4 o, gf;
    {
      float h = (accU[0] + ag0 + ub4.x)*bw + bb;
      float gx = ls4.x * fmaxf(0.f, yo0 + h);
      o[0] = gx + a4.x + x4.x; gf[0] = gx*0.5f;
    }{
      float h = (accU[1] + ag1 + ub4.y)*bw + bb;
      float gx = ls4.y * fmaxf(0.f, yo1 + h);
      o[1] = gx + a4.y + x4.y; gf[1] = gx*0.5f;
    }{
      float h = (accU[2] + ag2 + ub4.z)*bw + bb;
      float gx = ls4.z * fmaxf(0.f, yo2 + h);
      o[2] = gx + a4.z + x4.z; gf[2] = gx*0.5f;
    }{
      float h = (accU[3] + ag3 + ub4.w)*bw + bb;
      float gx = ls4.w * fmaxf(0.f, yo3 + h);
      o[3] = gx + a4.w + x4.w; gf[3] = gx*0.5f;
    }
    if (ok){
      *(f32x4*)(out+g)      = o;
      *(f32x4*)(out+NTOT+g) = gf;
    }
  }
}

extern "C" void kernel_launch(void* const* d_in, const int* in_sizes, int n_in,
                              void* d_out, int out_size, void* d_ws, size_t ws_size,
                              hipStream_t stream) {
  hipFuncSetAttribute(reinterpret_cast<const void*>(graphblock_kernel),
                      hipFuncAttributeMaxDynamicSharedMemorySize, SMEM_BYTES);
  dim3 grid(B_ * J_);
  dim3 block(1024);
  graphblock_kernel<<<grid, block, SMEM_BYTES, stream>>>(
      (const float*)d_in[0],  // x
      (const float*)d_in[1],  // attention_feat
      (const float*)d_in[2],  // ln_w
      (const float*)d_in[3],  // ln_b
      (const float*)d_in[4],  // Uw
      (const float*)d_in[5],  // Ub
      (const float*)d_in[6],  // Vw
      (const float*)d_in[7],  // Vb
      (const float*)d_in[8],  // bn_w
      (const float*)d_in[9],  // bn_b
      (const float*)d_in[10], // ls1
      (float*)d_out);
}

// Round 9
// 205.139 us; speedup vs baseline: 2.0537x; 1.0562x over previous
//
#include <hip/hip_runtime.h>

#define B_ 64
#define T_ 243
#define J_ 17
#define C_ 128
#define JC (J_*C_)            // 2176
#define NTOT (B_*T_*J_*C_)    // 33841152

// LDS layout (bytes). fp8 rows padded to 136 B (bank de-alias).
//   [0,     34816)  ylds : fp8 [256][136]
//   [34816, 69632)  yv   : fp8 [256][136]  (0.25*(y@Vw^T+Vb))
//   [69632, 71680)  nbr  : u64 [256]
//   [71680, 72704)  bnw_s: f32 [256] (pre-scaled)
//   [72704, 73728)  bnb_s: f32 [256]
//   [73728, 74240)  ub_s : f32 [128]
//   [74240, 74752)  ls_s : f32 [128]
#define YOFF    0
#define YVOFF   34816
#define NBROFF  69632
#define BNWOFF  71680
#define BNBOFF  72704
#define UBOFF   73728
#define LSOFF   74240
#define SMEM_BYTES 74752
#define YSTR 136

typedef float f32x4 __attribute__((ext_vector_type(4)));
typedef float f32x2 __attribute__((ext_vector_type(2)));

// pack 4 f32 -> 4 fp8(e4m3) in one dword
__device__ __forceinline__ unsigned pkf8(float a, float b, float c, float d){
  int p = __builtin_amdgcn_cvt_pk_fp8_f32(a, b, 0, false);
  p = __builtin_amdgcn_cvt_pk_fp8_f32(c, d, p, true);
  return (unsigned)p;
}

// 7-op insert of x into descending (a0>=a1>=a2>=a3)
#define PINS(x, a0,a1,a2,a3) do { \
  float t_ = fmaxf(a0,(x)), m_ = fminf(a0,(x)); a0 = t_; \
  float t2_ = fmaxf(a1,m_); m_ = fminf(a1,m_); a1 = t2_; \
  float t3_ = fmaxf(a2,m_); m_ = fminf(a2,m_); a2 = t3_; \
  a3 = fmaxf(a3,m_); \
} while(0)
#define MM(p,q) do { float h_=fmaxf(p,q); q=fminf(p,q); p=h_; } while(0)

extern "C" __global__ void __launch_bounds__(1024, 8)
graphblock_kernel(const float* __restrict__ x, const float* __restrict__ att,
                  const float* __restrict__ lnw, const float* __restrict__ lnb,
                  const float* __restrict__ Uw, const float* __restrict__ Ubv,
                  const float* __restrict__ Vw, const float* __restrict__ Vbv,
                  const float* __restrict__ bnw, const float* __restrict__ bnb,
                  const float* __restrict__ ls1, float* __restrict__ out)
{
  extern __shared__ char smem[];
  const int tid = threadIdx.x;
  const int w = tid >> 6, l = tid & 63;
  const int lr = l & 15, lg = l >> 4;
  const int n = blockIdx.x, b = n / J_, j = n % J_;
  const long nbase = (long)b*T_*JC + (long)j*C_;
  const int cs = w & 7, rh = w >> 3;
  const int ch0 = cs*16 + lg*4;        // lane's 4-channel base in UV passes

  // ---- table staging ----
  if (tid < 256) {
    bool v = tid < T_;
    ((float*)(smem+BNWOFF))[tid] = v ? bnw[tid]*rsqrtf(1.0f+1e-5f) : 0.f;
    ((float*)(smem+BNBOFF))[tid] = v ? bnb[tid] : 0.f;
  } else if (tid < 384) {
    int c = tid - 256;
    ((float*)(smem+UBOFF))[c] = Ubv[c];
    ((float*)(smem+LSOFF))[c] = ls1[c];
  }

  // ---- Phase A: LayerNorm -> ylds fp8 ; loads pipelined 8-deep ----
  {
    const int lh = l >> 5, lc = l & 31;
    const float4 lw4 = *(const float4*)(lnw + lc*4);
    const float4 lb4 = *(const float4*)(lnb + lc*4);
    float4 p[8];
    #pragma unroll
    for (int i=0;i<8;i++){
      const int r = i*32 + w*2 + lh;
      p[i] = make_float4(0.f,0.f,0.f,0.f);
      if (r < T_) p[i] = *(const float4*)(x + nbase + (long)r*JC + lc*4);
    }
    #pragma unroll
    for (int i=0;i<8;i++){
      const int r = i*32 + w*2 + lh;
      unsigned pk = 0u;
      if (r < T_) {
        float4 v = p[i];
        float s = (v.x+v.y)+(v.z+v.w);
        float q = (v.x*v.x+v.y*v.y)+(v.z*v.z+v.w*v.w);
        #pragma unroll
        for (int m=1;m<32;m<<=1){ s += __shfl_xor(s,m,64); q += __shfl_xor(q,m,64); }
        float mu = s*(1.f/128.f);
        float rs = rsqrtf(q*(1.f/128.f)-mu*mu+1e-5f);
        pk = pkf8((v.x-mu)*rs*lw4.x+lb4.x, (v.y-mu)*rs*lw4.y+lb4.y,
                  (v.z-mu)*rs*lw4.z+lb4.z, (v.w-mu)*rs*lw4.w+lb4.w);
      }
      *(unsigned*)(smem + YOFF + r*YSTR + lc*4) = pk;
    }
  }
  __syncthreads();   // barrier 1: ylds + tables ready

  // ---- Phase C: sim (fp8 MFMA) + in-register top-4 ----
  {
    const int ar = w*16 + lr;           // wave owns 16 t-rows
    long afr[4];
    #pragma unroll
    for (int kk=0;kk<4;kk++)
      afr[kk] = *(const long*)(smem + YOFF + ar*YSTR + kk*32 + lg*8);
    float v0[4],v1[4],v2[4],v3[4];
    #pragma unroll
    for (int r=0;r<4;r++){ v0[r]=-3e38f; v1[r]=-3e38f; v2[r]=-3e38f; v3[r]=-3e38f; }
    #pragma unroll 4
    for (int st=0; st<16; st++){
      f32x4 acc = {0.f,0.f,0.f,0.f};
      #pragma unroll
      for (int kk=0;kk<4;kk++){
        long bfr = *(const long*)(smem + YOFF + (st*16+lr)*YSTR + kk*32 + lg*8);
        acc = __builtin_amdgcn_mfma_f32_16x16x32_fp8_fp8(afr[kk], bfr, acc, 0,0,0);
      }
      const int sidx = st*16 + lr;
      const bool okc = sidx < T_;
      #pragma unroll
      for (int reg=0;reg<4;reg++){
        unsigned u = (__float_as_uint(acc[reg]) & 0xffffff00u) | (unsigned)sidx;
        float pv = okc ? __uint_as_float(u) : -3e38f;
        PINS(pv, v0[reg],v1[reg],v2[reg],v3[reg]);
      }
    }
    #pragma unroll
    for (int m=1;m<16;m<<=1){
      #pragma unroll
      for (int reg=0;reg<4;reg++){
        float c0=__shfl_xor(v0[reg],m,64), c1=__shfl_xor(v1[reg],m,64),
              c2=__shfl_xor(v2[reg],m,64), c3=__shfl_xor(v3[reg],m,64);
        float d0=fmaxf(v0[reg],c3), d1=fmaxf(v1[reg],c2),
              d2=fmaxf(v2[reg],c1), d3=fmaxf(v3[reg],c0);
        MM(d0,d1); MM(d2,d3); MM(d0,d2); MM(d1,d3); MM(d1,d2);
        v0[reg]=d0; v1[reg]=d1; v2[reg]=d2; v3[reg]=d3;
      }
    }
    if (lr==0){
      #pragma unroll
      for (int reg=0;reg<4;reg++){
        int row = w*16 + lg*4 + reg;
        unsigned long long pk =
            (unsigned long long)(__float_as_uint(v0[reg]) & 0xffu)
          | ((unsigned long long)(__float_as_uint(v1[reg]) & 0xffu) << 16)
          | ((unsigned long long)(__float_as_uint(v2[reg]) & 0xffu) << 32)
          | ((unsigned long long)(__float_as_uint(v3[reg]) & 0xffu) << 48);
        *(unsigned long long*)(smem + NBROFF + row*8) = pk;
      }
    }
  }

  // ---- load + quantize weights to fp8 frags (A-operand: row=out-channel) ----
  long ufr[4], vfr[4];
  {
    const int crw = cs*16 + lr;
    #pragma unroll
    for (int kk=0;kk<4;kk++){
      const float4* pu = (const float4*)(Uw + crw*C_ + kk*32 + lg*8);
      float4 a = pu[0], c = pu[1];
      union { long v; unsigned u[2]; } r;
      r.u[0] = pkf8(a.x,a.y,a.z,a.w); r.u[1] = pkf8(c.x,c.y,c.z,c.w);
      ufr[kk] = r.v;
      const float4* pv = (const float4*)(Vw + crw*C_ + kk*32 + lg*8);
      a = pv[0]; c = pv[1];
      r.u[0] = pkf8(a.x,a.y,a.z,a.w); r.u[1] = pkf8(c.x,c.y,c.z,c.w);
      vfr[kk] = r.v;
    }
  }
  const float4 vb4 = *(const float4*)(Vbv + ch0);

  // ---- Pass 1: yv = 0.25*(y@Vw^T + Vb) -> fp8 LDS ----
  #pragma unroll 2
  for (int tt=0; tt<8; tt++){
    const int t = (rh*8+tt)*16 + lr;
    f32x4 accV = {0.f,0.f,0.f,0.f};
    #pragma unroll
    for (int kk=0;kk<4;kk++){
      long yf = *(const long*)(smem + YOFF + t*YSTR + kk*32 + lg*8);
      accV = __builtin_amdgcn_mfma_f32_16x16x32_fp8_fp8(vfr[kk], yf, accV, 0,0,0);
    }
    *(unsigned*)(smem + YVOFF + t*YSTR + ch0) =
        pkf8(0.25f*(accV[0]+vb4.x), 0.25f*(accV[1]+vb4.y),
             0.25f*(accV[2]+vb4.z), 0.25f*(accV[3]+vb4.w));
  }
  __syncthreads();   // barrier 2: nbr + yv ready

  // ---- Pass 2: yU MFMA + gather + BN + ReLU + epilogue, x/att prefetch 1-ahead ----
  const float4 ub4 = *(const float4*)((const float*)(smem+UBOFF) + ch0);
  const float4 ls4 = *(const float4*)((const float*)(smem+LSOFF) + ch0);

  int   t_n  = (rh*8)*16 + lr;
  bool  ok_n = t_n < T_;
  long  g_n  = nbase + (long)t_n*JC + ch0;
  float4 px = make_float4(0,0,0,0), pa = make_float4(0,0,0,0);
  if (ok_n){ px = *(const float4*)(x+g_n); pa = *(const float4*)(att+g_n); }

  #pragma unroll
  for (int tt=0; tt<8; tt++){
    const int   t  = t_n;
    const bool  ok = ok_n;
    const long  g  = g_n;
    const float4 x4 = px, a4 = pa;
    if (tt < 7){
      t_n  = (rh*8+tt+1)*16 + lr;
      ok_n = t_n < T_;
      g_n  = nbase + (long)t_n*JC + ch0;
      px = make_float4(0,0,0,0); pa = make_float4(0,0,0,0);
      if (ok_n){ px = *(const float4*)(x+g_n); pa = *(const float4*)(att+g_n); }
    }
    f32x4 accU = {0.f,0.f,0.f,0.f};
    #pragma unroll
    for (int kk=0;kk<4;kk++){
      long yf = *(const long*)(smem + YOFF + t*YSTR + kk*32 + lg*8);
      accU = __builtin_amdgcn_mfma_f32_16x16x32_fp8_fp8(ufr[kk], yf, accU, 0,0,0);
    }
    unsigned long long nb = *(const unsigned long long*)(smem + NBROFF + t*8);
    const int s0 = (int)(nb & 0xffu), s1 = (int)((nb>>16)&0xffu),
              s2 = (int)((nb>>32)&0xffu), s3 = (int)((nb>>48)&0xffu);
    float ag0=0,ag1=0,ag2=0,ag3=0;
    {
      unsigned q; f32x2 e, o2;
      q = *(const unsigned*)(smem+YVOFF + s0*YSTR + ch0);
      e = __builtin_amdgcn_cvt_pk_f32_fp8(q,false); o2 = __builtin_amdgcn_cvt_pk_f32_fp8(q,true);
      ag0+=e[0]; ag1+=e[1]; ag2+=o2[0]; ag3+=o2[1];
      q = *(const unsigned*)(smem+YVOFF + s1*YSTR + ch0);
      e = __builtin_amdgcn_cvt_pk_f32_fp8(q,false); o2 = __builtin_amdgcn_cvt_pk_f32_fp8(q,true);
      ag0+=e[0]; ag1+=e[1]; ag2+=o2[0]; ag3+=o2[1];
      q = *(const unsigned*)(smem+YVOFF + s2*YSTR + ch0);
      e = __builtin_amdgcn_cvt_pk_f32_fp8(q,false); o2 = __builtin_amdgcn_cvt_pk_f32_fp8(q,true);
      ag0+=e[0]; ag1+=e[1]; ag2+=o2[0]; ag3+=o2[1];
      q = *(const unsigned*)(smem+YVOFF + s3*YSTR + ch0);
      e = __builtin_amdgcn_cvt_pk_f32_fp8(q,false); o2 = __builtin_amdgcn_cvt_pk_f32_fp8(q,true);
      ag0+=e[0]; ag1+=e[1]; ag2+=o2[0]; ag3+=o2[1];
    }
    float yo0,yo1,yo2,yo3;
    {
      unsigned q = *(const unsigned*)(smem + YOFF + t*YSTR + ch0);
      f32x2 e = __builtin_amdgcn_cvt_pk_f32_fp8(q,false);
      f32x2 o2 = __builtin_amdgcn_cvt_pk_f32_fp8(q,true);
      yo0=e[0]; yo1=e[1]; yo2=o2[0]; yo3=o2[1];
    }
    const float bw = ((const float*)(smem+BNWOFF))[t];
    const float bb = ((const float*)(smem+BNBOFF))[t];
    f32x4 o, gf;
    {
      float h = (accU[0] + ag0 + ub4.x)*bw + bb;
      float gx = ls4.x * fmaxf(0.f, yo0 + h);
      o[0] = gx + a4.x + x4.x; gf[0] = gx*0.5f;
    }{
      float h = (accU[1] + ag1 + ub4.y)*bw + bb;
      float gx = ls4.y * fmaxf(0.f, yo1 + h);
      o[1] = gx + a4.y + x4.y; gf[1] = gx*0.5f;
    }{
      float h = (accU[2] + ag2 + ub4.z)*bw + bb;
      float gx = ls4.z * fmaxf(0.f, yo2 + h);
      o[2] = gx + a4.z + x4.z; gf[2] = gx*0.5f;
    }{
      float h = (accU[3] + ag3 + ub4.w)*bw + bb;
      float gx = ls4.w * fmaxf(0.f, yo3 + h);
      o[3] = gx + a4.w + x4.w; gf[3] = gx*0.5f;
    }
    if (ok){
      *(f32x4*)(out+g)      = o;
      *(f32x4*)(out+NTOT+g) = gf;
    }
  }
}

extern "C" void kernel_launch(void* const* d_in, const int* in_sizes, int n_in,
                              void* d_out, int out_size, void* d_ws, size_t ws_size,
                              hipStream_t stream) {
  hipFuncSetAttribute(reinterpret_cast<const void*>(graphblock_kernel),
                      hipFuncAttributeMaxDynamicSharedMemorySize, SMEM_BYTES);
  dim3 grid(B_ * J_);
  dim3 block(1024);
  graphblock_kernel<<<grid, block, SMEM_BYTES, stream>>>(
      (const float*)d_in[0],  // x
      (const float*)d_in[1],  // attention_feat
      (const float*)d_in[2],  // ln_w
      (const float*)d_in[3],  // ln_b
      (const float*)d_in[4],  // Uw
      (const float*)d_in[5],  // Ub
      (const float*)d_in[6],  // Vw
      (const float*)d_in[7],  // Vb
      (const float*)d_in[8],  // bn_w
      (const float*)d_in[9],  // bn_b
      (const float*)d_in[10], // ls1
      (float*)d_out);
}

// Round 11
// 194.698 us; speedup vs baseline: 2.1638x; 1.0536x over previous
//
#include <hip/hip_runtime.h>

#define B_ 64
#define T_ 243
#define J_ 17
#define C_ 128
#define JC (J_*C_)            // 2176
#define NTOT (B_*T_*J_*C_)    // 33841152

// LDS layout (bytes). fp8 rows padded to 136 B (bank de-alias).
//   [0,     34816)  ylds : fp8 [256][136]
//   [34816, 69632)  yv   : fp8 [256][136]  (0.25*(y@Vw^T+Vb))
//   [69632, 70656)  nbr  : u32 [256]  (4 x u8 idx)
//   [70656, 71680)  bnw_s: f32 [256] (pre-scaled)
//   [71680, 72704)  bnb_s: f32 [256]
//   [72704, 73216)  ub_s : f32 [128]
//   [73216, 73728)  ls_s : f32 [128]
#define YOFF    0
#define YVOFF   34816
#define NBROFF  69632
#define BNWOFF  70656
#define BNBOFF  71680
#define UBOFF   72704
#define LSOFF   73216
#define SMEM_BYTES 73728
#define YSTR 136

typedef float f32x4 __attribute__((ext_vector_type(4)));
typedef float f32x2 __attribute__((ext_vector_type(2)));

// pack 4 f32 -> 4 fp8(e4m3) in one dword
__device__ __forceinline__ unsigned pkf8(float a, float b, float c, float d){
  int p = __builtin_amdgcn_cvt_pk_fp8_f32(a, b, 0, false);
  p = __builtin_amdgcn_cvt_pk_fp8_f32(c, d, p, true);
  return (unsigned)p;
}

// DPP add: v += v permuted by CTRL (VALU pipe, no LDS). CTRL must be ICE.
template<int CTRL>
__device__ __forceinline__ float dppadd(float v){
  int t = __builtin_amdgcn_update_dpp(0, __float_as_int(v), CTRL, 0xf, 0xf, true);
  return v + __int_as_float(t);
}
// ds_swizzle xor-16 within each 32-lane half
__device__ __forceinline__ float swz16(float v){
  return __int_as_float(__builtin_amdgcn_ds_swizzle(__float_as_int(v), 0x401F));
}

// 7-op insert of x into descending (a0>=a1>=a2>=a3)
#define PINS(x, a0,a1,a2,a3) do { \
  float t_ = fmaxf(a0,(x)), m_ = fminf(a0,(x)); a0 = t_; \
  float t2_ = fmaxf(a1,m_); m_ = fminf(a1,m_); a1 = t2_; \
  float t3_ = fmaxf(a2,m_); m_ = fminf(a2,m_); a2 = t3_; \
  a3 = fmaxf(a3,m_); \
} while(0)
#define MM(p,q) do { float h_=fmaxf(p,q); q=fminf(p,q); p=h_; } while(0)

extern "C" __global__ void __launch_bounds__(1024, 8)
graphblock_kernel(const float* __restrict__ x, const float* __restrict__ att,
                  const float* __restrict__ lnw, const float* __restrict__ lnb,
                  const float* __restrict__ Uw, const float* __restrict__ Ubv,
                  const float* __restrict__ Vw, const float* __restrict__ Vbv,
                  const float* __restrict__ bnw, const float* __restrict__ bnb,
                  const float* __restrict__ ls1, float* __restrict__ out)
{
  extern __shared__ char smem[];
  const int tid = threadIdx.x;
  const int w = tid >> 6, l = tid & 63;
  const int lr = l & 15, lg = l >> 4;
  const int n = blockIdx.x, b = n / J_, j = n % J_;
  const long nbase = (long)b*T_*JC + (long)j*C_;
  const int cs = w & 7, rh = w >> 3;
  const int ch0 = cs*16 + lg*4;        // lane's 4-channel base in UV passes

  // ---- table staging ----
  if (tid < 256) {
    bool v = tid < T_;
    ((float*)(smem+BNWOFF))[tid] = v ? bnw[tid]*rsqrtf(1.0f+1e-5f) : 0.f;
    ((float*)(smem+BNBOFF))[tid] = v ? bnb[tid] : 0.f;
  } else if (tid < 384) {
    int c = tid - 256;
    ((float*)(smem+UBOFF))[c] = Ubv[c];
    ((float*)(smem+LSOFF))[c] = ls1[c];
  }

  // ---- Phase A: LayerNorm -> ylds fp8 ; DPP reductions ----
  {
    const int lh = l >> 5, lc = l & 31;
    const float4 lw4 = *(const float4*)(lnw + lc*4);
    const float4 lb4 = *(const float4*)(lnb + lc*4);
    float4 p[8];
    #pragma unroll
    for (int i=0;i<8;i++){
      const int r = i*32 + w*2 + lh;
      p[i] = make_float4(0.f,0.f,0.f,0.f);
      if (r < T_) p[i] = *(const float4*)(x + nbase + (long)r*JC + lc*4);
    }
    #pragma unroll
    for (int i=0;i<8;i++){
      const int r = i*32 + w*2 + lh;
      unsigned pk = 0u;
      if (r < T_) {
        float4 v = p[i];
        float s = (v.x+v.y)+(v.z+v.w);
        float q = (v.x*v.x+v.y*v.y)+(v.z*v.z+v.w*v.w);
        s = dppadd<0xB1>(s);  q = dppadd<0xB1>(q);   // quad xor1
        s = dppadd<0x4E>(s);  q = dppadd<0x4E>(q);   // quad xor2
        s = dppadd<0x124>(s); q = dppadd<0x124>(q);  // row_ror:4
        s = dppadd<0x128>(s); q = dppadd<0x128>(q);  // row_ror:8
        s += swz16(s);        q += swz16(q);         // xor16 (32-lane span)
        float mu = s*(1.f/128.f);
        float rs = rsqrtf(q*(1.f/128.f)-mu*mu+1e-5f);
        pk = pkf8((v.x-mu)*rs*lw4.x+lb4.x, (v.y-mu)*rs*lw4.y+lb4.y,
                  (v.z-mu)*rs*lw4.z+lb4.z, (v.w-mu)*rs*lw4.w+lb4.w);
      }
      *(unsigned*)(smem + YOFF + r*YSTR + lc*4) = pk;
    }
  }
  __syncthreads();   // barrier 1: ylds + tables ready

  // ---- Phase C: sim (fp8 MFMA, swapped operands) + per-lane top-4 ----
  {
    const int tcol = w*16 + lr;         // this lane's t (D column)
    long bfr[4];
    #pragma unroll
    for (int kk=0;kk<4;kk++)
      bfr[kk] = *(const long*)(smem + YOFF + tcol*YSTR + kk*32 + lg*8);
    float v0=-3e38f, v1=-3e38f, v2=-3e38f, v3=-3e38f;
    #pragma unroll 4
    for (int st=0; st<16; st++){
      f32x4 acc = {0.f,0.f,0.f,0.f};
      #pragma unroll
      for (int kk=0;kk<4;kk++){
        long afr = *(const long*)(smem + YOFF + (st*16+lr)*YSTR + kk*32 + lg*8);
        acc = __builtin_amdgcn_mfma_f32_16x16x32_fp8_fp8(afr, bfr[kk], acc, 0,0,0);
      }
      #pragma unroll
      for (int reg=0;reg<4;reg++){
        const int sidx = st*16 + lg*4 + reg;   // D row = s
        unsigned u = (__float_as_uint(acc[reg]) & 0xffffff00u) | (unsigned)(sidx & 0xff);
        float pv = (sidx < T_) ? __uint_as_float(u) : -3e38f;
        PINS(pv, v0,v1,v2,v3);
      }
    }
    // merge across lg (lanes l^16, l^32): 2 sorted-merge steps
    #pragma unroll
    for (int m=16;m<64;m<<=1){
      float c0=__shfl_xor(v0,m,64), c1=__shfl_xor(v1,m,64),
            c2=__shfl_xor(v2,m,64), c3=__shfl_xor(v3,m,64);
      float d0=fmaxf(v0,c3), d1=fmaxf(v1,c2), d2=fmaxf(v2,c1), d3=fmaxf(v3,c0);
      MM(d0,d1); MM(d2,d3); MM(d0,d2); MM(d1,d3); MM(d1,d2);
      v0=d0; v1=d1; v2=d2; v3=d3;
    }
    if (lg==0){
      unsigned pk = (__float_as_uint(v0) & 0xffu)
                  | ((__float_as_uint(v1) & 0xffu) << 8)
                  | ((__float_as_uint(v2) & 0xffu) << 16)
                  | ((__float_as_uint(v3) & 0xffu) << 24);
      *(unsigned*)(smem + NBROFF + tcol*4) = pk;
    }
  }

  // ---- load + quantize weights to fp8 frags (A-operand: row=out-channel) ----
  long ufr[4], vfr[4];
  {
    const int crw = cs*16 + lr;
    #pragma unroll
    for (int kk=0;kk<4;kk++){
      const float4* pu = (const float4*)(Uw + crw*C_ + kk*32 + lg*8);
      float4 a = pu[0], c = pu[1];
      union { long v; unsigned u[2]; } r;
      r.u[0] = pkf8(a.x,a.y,a.z,a.w); r.u[1] = pkf8(c.x,c.y,c.z,c.w);
      ufr[kk] = r.v;
      const float4* pv = (const float4*)(Vw + crw*C_ + kk*32 + lg*8);
      a = pv[0]; c = pv[1];
      r.u[0] = pkf8(a.x,a.y,a.z,a.w); r.u[1] = pkf8(c.x,c.y,c.z,c.w);
      vfr[kk] = r.v;
    }
  }
  const float4 vb4 = *(const float4*)(Vbv + ch0);

  // ---- Pass 1: yv = 0.25*(y@Vw^T + Vb) -> fp8 LDS ----
  #pragma unroll 2
  for (int tt=0; tt<8; tt++){
    const int t = (rh*8+tt)*16 + lr;
    f32x4 accV = {0.f,0.f,0.f,0.f};
    #pragma unroll
    for (int kk=0;kk<4;kk++){
      long yf = *(const long*)(smem + YOFF + t*YSTR + kk*32 + lg*8);
      accV = __builtin_amdgcn_mfma_f32_16x16x32_fp8_fp8(vfr[kk], yf, accV, 0,0,0);
    }
    *(unsigned*)(smem + YVOFF + t*YSTR + ch0) =
        pkf8(0.25f*(accV[0]+vb4.x), 0.25f*(accV[1]+vb4.y),
             0.25f*(accV[2]+vb4.z), 0.25f*(accV[3]+vb4.w));
  }
  __syncthreads();   // barrier 2: nbr + yv ready

  // ---- Pass 2: yU MFMA + gather + BN + ReLU + epilogue, x/att prefetch 1-ahead ----
  const float4 ub4 = *(const float4*)((const float*)(smem+UBOFF) + ch0);
  const float4 ls4 = *(const float4*)((const float*)(smem+LSOFF) + ch0);

  int   t_n  = (rh*8)*16 + lr;
  bool  ok_n = t_n < T_;
  long  g_n  = nbase + (long)t_n*JC + ch0;
  float4 px = make_float4(0,0,0,0), pa = make_float4(0,0,0,0);
  if (ok_n){ px = *(const float4*)(x+g_n); pa = *(const float4*)(att+g_n); }

  #pragma unroll
  for (int tt=0; tt<8; tt++){
    const int   t  = t_n;
    const bool  ok = ok_n;
    const long  g  = g_n;
    const float4 x4 = px, a4 = pa;
    if (tt < 7){
      t_n  = (rh*8+tt+1)*16 + lr;
      ok_n = t_n < T_;
      g_n  = nbase + (long)t_n*JC + ch0;
      px = make_float4(0,0,0,0); pa = make_float4(0,0,0,0);
      if (ok_n){ px = *(const float4*)(x+g_n); pa = *(const float4*)(att+g_n); }
    }
    f32x4 accU = {0.f,0.f,0.f,0.f};
    #pragma unroll
    for (int kk=0;kk<4;kk++){
      long yf = *(const long*)(smem + YOFF + t*YSTR + kk*32 + lg*8);
      accU = __builtin_amdgcn_mfma_f32_16x16x32_fp8_fp8(ufr[kk], yf, accU, 0,0,0);
    }
    unsigned nb = *(const unsigned*)(smem + NBROFF + t*4);
    const int s0 = (int)(nb & 0xffu), s1 = (int)((nb>>8)&0xffu),
              s2 = (int)((nb>>16)&0xffu), s3 = (int)((nb>>24)&0xffu);
    float ag0=0,ag1=0,ag2=0,ag3=0;
    {
      unsigned q; f32x2 e, o2;
      q = *(const unsigned*)(smem+YVOFF + s0*YSTR + ch0);
      e = __builtin_amdgcn_cvt_pk_f32_fp8(q,false); o2 = __builtin_amdgcn_cvt_pk_f32_fp8(q,true);
      ag0+=e[0]; ag1+=e[1]; ag2+=o2[0]; ag3+=o2[1];
      q = *(const unsigned*)(smem+YVOFF + s1*YSTR + ch0);
      e = __builtin_amdgcn_cvt_pk_f32_fp8(q,false); o2 = __builtin_amdgcn_cvt_pk_f32_fp8(q,true);
      ag0+=e[0]; ag1+=e[1]; ag2+=o2[0]; ag3+=o2[1];
      q = *(const unsigned*)(smem+YVOFF + s2*YSTR + ch0);
      e = __builtin_amdgcn_cvt_pk_f32_fp8(q,false); o2 = __builtin_amdgcn_cvt_pk_f32_fp8(q,true);
      ag0+=e[0]; ag1+=e[1]; ag2+=o2[0]; ag3+=o2[1];
      q = *(const unsigned*)(smem+YVOFF + s3*YSTR + ch0);
      e = __builtin_amdgcn_cvt_pk_f32_fp8(q,false); o2 = __builtin_amdgcn_cvt_pk_f32_fp8(q,true);
      ag0+=e[0]; ag1+=e[1]; ag2+=o2[0]; ag3+=o2[1];
    }
    float yo0,yo1,yo2,yo3;
    {
      unsigned q = *(const unsigned*)(smem + YOFF + t*YSTR + ch0);
      f32x2 e = __builtin_amdgcn_cvt_pk_f32_fp8(q,false);
      f32x2 o2 = __builtin_amdgcn_cvt_pk_f32_fp8(q,true);
      yo0=e[0]; yo1=e[1]; yo2=o2[0]; yo3=o2[1];
    }
    const float bw = ((const float*)(smem+BNWOFF))[t];
    const float bb = ((const float*)(smem+BNBOFF))[t];
    f32x4 o, gf;
    {
      float h = (accU[0] + ag0 + ub4.x)*bw + bb;
      float gx = ls4.x * fmaxf(0.f, yo0 + h);
      o[0] = gx + a4.x + x4.x; gf[0] = gx*0.5f;
    }{
      float h = (accU[1] + ag1 + ub4.y)*bw + bb;
      float gx = ls4.y * fmaxf(0.f, yo1 + h);
      o[1] = gx + a4.y + x4.y; gf[1] = gx*0.5f;
    }{
      float h = (accU[2] + ag2 + ub4.z)*bw + bb;
      float gx = ls4.z * fmaxf(0.f, yo2 + h);
      o[2] = gx + a4.z + x4.z; gf[2] = gx*0.5f;
    }{
      float h = (accU[3] + ag3 + ub4.w)*bw + bb;
      float gx = ls4.w * fmaxf(0.f, yo3 + h);
      o[3] = gx + a4.w + x4.w; gf[3] = gx*0.5f;
    }
    if (ok){
      *(f32x4*)(out+g)      = o;
      *(f32x4*)(out+NTOT+g) = gf;
    }
  }
}

extern "C" void kernel_launch(void* const* d_in, const int* in_sizes, int n_in,
                              void* d_out, int out_size, void* d_ws, size_t ws_size,
                              hipStream_t stream) {
  hipFuncSetAttribute(reinterpret_cast<const void*>(graphblock_kernel),
                      hipFuncAttributeMaxDynamicSharedMemorySize, SMEM_BYTES);
  dim3 grid(B_ * J_);
  dim3 block(1024);
  graphblock_kernel<<<grid, block, SMEM_BYTES, stream>>>(
      (const float*)d_in[0],  // x
      (const float*)d_in[1],  // attention_feat
      (const float*)d_in[2],  // ln_w
      (const float*)d_in[3],  // ln_b
      (const float*)d_in[4],  // Uw
      (const float*)d_in[5],  // Ub
      (const float*)d_in[6],  // Vw
      (const float*)d_in[7],  // Vb
      (const float*)d_in[8],  // bn_w
      (const float*)d_in[9],  // bn_b
      (const float*)d_in[10], // ls1
      (float*)d_out);
}